// Round 7
// baseline (276.311 us; speedup 1.0000x reference)
//
#include <hip/hip_runtime.h>
#include <hip/hip_fp16.h>

// Problem constants
#define NB 4      // batch
#define CI 256    // input channels
#define HH 64
#define WW 64
#define MC 64     // compressed channels
#define HS 128    // H*2
#define WS_ 128   // W*2
#define HW 4096   // HH*WW
// wpack: [n][sh:2][pix:4096][28] uints; each uint = half2 (q=2sh, q=2sh+1)

typedef __attribute__((ext_vector_type(8))) short short8v;   // 8 bf16 (4 VGPRs)
typedef __attribute__((ext_vector_type(4))) float floatx4;   // MFMA C/D

__device__ inline unsigned short f2bf(float f) {
  union { float f; unsigned u; } v; v.f = f;
  unsigned r = v.u + 0x7FFFu + ((v.u >> 16) & 1u);   // RNE
  return (unsigned short)(r >> 16);
}

// ---------------------------------------------------------------------------
// Prep: rearrange weights into MFMA A-fragment layout (bf16).
// ---------------------------------------------------------------------------
__global__ __launch_bounds__(256) void prep_kernel(
    const float* __restrict__ w_comp, const float* __restrict__ w_enc,
    unsigned short* __restrict__ Aw1, unsigned short* __restrict__ Aw2) {
  int i = blockIdx.x * 256 + threadIdx.x;
  if (i < 16384) {                       // 8*64*32
    int kl = i & 31, o = (i >> 5) & 63, ks = i >> 11;
    Aw1[i] = f2bf(w_comp[o * 256 + ks * 32 + kl]);
  } else if (i < 16384 + 64512) {        // 18*112*32
    int j = i - 16384;
    int kl = j & 31, o = (j >> 5) % 112, ks = (j >> 5) / 112;
    int t = ks >> 1, m = (ks & 1) * 32 + kl;
    Aw2[j] = (o < 100) ? f2bf(w_enc[o * 576 + m * 9 + t]) : (unsigned short)0;
  }
}

// ---------------------------------------------------------------------------
// Kernel 1: 1x1 conv via MFMA, K-split 2 (unchanged).
// ---------------------------------------------------------------------------
__global__ __launch_bounds__(512, 1) void conv1x1_mfma(
    const float* __restrict__ x, const unsigned short* __restrict__ Aw1,
    const float* __restrict__ b_comp, unsigned short* __restrict__ comp_cl) {
  __shared__ float pacc[4][64][17];
  int tid = threadIdx.x;
  int wid = tid >> 6, lane = tid & 63;
  int tileid = wid & 3, kh = wid >> 2;
  int Nt = blockIdx.x * 4 + tileid;       // 0..1023
  int n = Nt >> 8, pixbase = (Nt & 255) * 16;
  int l15 = lane & 15, g = lane >> 4;
  int pix = pixbase + l15;

  floatx4 acc[4];
#pragma unroll
  for (int ot = 0; ot < 4; ++ot) acc[ot] = (floatx4){0.f, 0.f, 0.f, 0.f};

  const float* xb = x + (size_t)n * CI * HW + pix;
  const unsigned short* ab = Aw1 + l15 * 32 + g * 8;

#pragma unroll
  for (int s = 0; s < 4; ++s) {
    int ks = kh * 4 + s;
    int c0 = ks * 32 + g * 8;
    short8v bfrag;
#pragma unroll
    for (int j = 0; j < 8; ++j)
      bfrag[j] = (short)f2bf(xb[(size_t)(c0 + j) * HW]);
#pragma unroll
    for (int ot = 0; ot < 4; ++ot) {
      short8v af = *(const short8v*)(ab + (ks * 64 + ot * 16) * 32);
      acc[ot] = __builtin_amdgcn_mfma_f32_16x16x32_bf16(af, bfrag, acc[ot], 0, 0, 0);
    }
  }

  if (kh == 1) {
#pragma unroll
    for (int ot = 0; ot < 4; ++ot)
#pragma unroll
      for (int r = 0; r < 4; ++r) pacc[tileid][lane][ot * 4 + r] = acc[ot][r];
  }
  __syncthreads();
  if (kh == 0) {
    unsigned short* cp = comp_cl + ((size_t)(n * HW + pix)) * 64;
#pragma unroll
    for (int ot = 0; ot < 4; ++ot) {
      const float4 bv = *(const float4*)(b_comp + ot * 16 + g * 4);
      float v0 = acc[ot][0] + pacc[tileid][lane][ot * 4 + 0] + bv.x;
      float v1 = acc[ot][1] + pacc[tileid][lane][ot * 4 + 1] + bv.y;
      float v2 = acc[ot][2] + pacc[tileid][lane][ot * 4 + 2] + bv.z;
      float v3 = acc[ot][3] + pacc[tileid][lane][ot * 4 + 3] + bv.w;
      unsigned h01 = (unsigned)f2bf(v0) | ((unsigned)f2bf(v1) << 16);
      unsigned h23 = (unsigned)f2bf(v2) | ((unsigned)f2bf(v3) << 16);
      *(int2*)(cp + ot * 16 + g * 4) = make_int2((int)h01, (int)h23);
    }
  }
}

// ---------------------------------------------------------------------------
// Kernel 2: 3x3 conv + pixel-shuffle + softmax(25), K-split 2 (unchanged).
// Packs f16 weight pairs: wpack[n][sh][pix][28], uint = half2(q=2sh, q=2sh+1).
// ---------------------------------------------------------------------------
__global__ __launch_bounds__(512, 1) void kenc_mfma(
    const unsigned short* __restrict__ comp_cl,
    const unsigned short* __restrict__ Aw2,
    const float* __restrict__ b_enc, unsigned int* __restrict__ wpack) {
  __shared__ float pacc[4][64][29];
  int tid = threadIdx.x;
  int wid = tid >> 6, lane = tid & 63;
  int tileid = wid & 3, kh = wid >> 2;
  int Nt = blockIdx.x * 4 + tileid;       // 0..1023
  int n = Nt >> 8, pixbase = (Nt & 255) * 16;
  int l15 = lane & 15, g = lane >> 4;
  int pix = pixbase + l15;
  int y = pix >> 6, xcol = pix & 63;

  bool vm[9];
  int sh9[9];
#pragma unroll
  for (int t = 0; t < 9; ++t) {
    int dy = t / 3, dx = t % 3;
    vm[t] = ((unsigned)(y + dy - 1) < 64u) && ((unsigned)(xcol + dx - 1) < 64u);
    sh9[t] = (dy - 1) * 64 + (dx - 1);
  }

  floatx4 acc[7];
#pragma unroll
  for (int ot = 0; ot < 7; ++ot) acc[ot] = (floatx4){0.f, 0.f, 0.f, 0.f};

  const unsigned short* cb = comp_cl + (size_t)n * HW * 64;
  const unsigned short* ab = Aw2 + l15 * 32 + g * 8;
  const short8v zv = {0, 0, 0, 0, 0, 0, 0, 0};

#pragma unroll
  for (int s = 0; s < 9; ++s) {
    int ks = kh * 9 + s;
    int t = ks >> 1, mh = ks & 1;
    const unsigned short* bp = cb + (pix + sh9[t]) * 64 + mh * 32 + g * 8;
    short8v bfrag = vm[t] ? *(const short8v*)bp : zv;
#pragma unroll
    for (int ot = 0; ot < 7; ++ot) {
      short8v af = *(const short8v*)(ab + (ks * 112 + ot * 16) * 32);
      acc[ot] = __builtin_amdgcn_mfma_f32_16x16x32_bf16(af, bfrag, acc[ot], 0, 0, 0);
    }
  }

  if (kh == 1) {
#pragma unroll
    for (int ot = 0; ot < 7; ++ot)
#pragma unroll
      for (int r = 0; r < 4; ++r) pacc[tileid][lane][ot * 4 + r] = acc[ot][r];
  }
  __syncthreads();
  if (kh == 0) {
#pragma unroll
    for (int ot = 0; ot < 7; ++ot) {
      int ob = ot * 16 + g * 4; if (ob > 96) ob = 96;
      const float4 bv = *(const float4*)(b_enc + ob);
      acc[ot][0] += pacc[tileid][lane][ot * 4 + 0] + bv.x;
      acc[ot][1] += pacc[tileid][lane][ot * 4 + 1] + bv.y;
      acc[ot][2] += pacc[tileid][lane][ot * 4 + 2] + bv.z;
      acc[ot][3] += pacc[tileid][lane][ot * 4 + 3] + bv.w;
    }

    // per-r softmax; write normalized values back into acc[ot][r]
#pragma unroll
    for (int r = 0; r < 4; ++r) {
      float m = acc[0][r];
#pragma unroll
      for (int ot = 1; ot < 6; ++ot) m = fmaxf(m, acc[ot][r]);
      if (g == 0) m = fmaxf(m, acc[6][r]);
      m = fmaxf(m, __shfl_xor(m, 16));
      m = fmaxf(m, __shfl_xor(m, 32));
      float s = 0.f;
      float e[7];
#pragma unroll
      for (int ot = 0; ot < 7; ++ot) {
        bool val = (ot < 6) || (g == 0);
        e[ot] = val ? __expf(acc[ot][r] - m) : 0.f;
        s += e[ot];
      }
      s += __shfl_xor(s, 16);
      s += __shfl_xor(s, 32);
      float inv = 1.f / s;
#pragma unroll
      for (int ot = 0; ot < 7; ++ot) acc[ot][r] = e[ot] * inv;
    }

    // pack f16 pairs and store: k = ot*4+g (valid k<25)
#pragma unroll
    for (int sh = 0; sh < 2; ++sh) {
      unsigned int* wq = wpack + ((size_t)((n * 2 + sh) * HW) + pix) * 28;
#pragma unroll
      for (int ot = 0; ot < 7; ++ot) {
        if ((ot < 6) || (g == 0)) {
          __half2 h2 = __floats2half2_rn(acc[ot][2 * sh], acc[ot][2 * sh + 1]);
          wq[ot * 4 + g] = *reinterpret_cast<unsigned int*>(&h2);
        }
      }
    }
  }
}

// ---------------------------------------------------------------------------
// Kernel 3: reassembly v6.
// Thread = one input pixel's 2x2 output quad x 16 channels (8 iters).
// All 4 outputs share ONE 5x5 patch -> 100 FMA per 25 conflict-free b32
// LDS reads. Weights = both sh-planes of one pixel = 50 packed f16-pair
// dwords, loaded as NAMED uint4s (no address casts -> SROA keeps them in
// VGPRs; round-6 lesson). LDS 36.9 KB -> 4 blocks/CU; ~75 VGPR -> 4 w/SIMD.
// ---------------------------------------------------------------------------
__global__ __launch_bounds__(256, 4) void reassembly_kernel(
    const float* __restrict__ x, const unsigned int* __restrict__ wpack,
    float* __restrict__ out) {
  __shared__ float xpatch[128 * 72];    // [c][r:6][col:12]
  int tid = threadIdx.x;
  int bid = blockIdx.x;                 // tile(256) | n(4) | cg(2)
  int tile = bid & 255;
  int n = (bid >> 8) & 3;
  int cg = bid >> 10;
  int tyi = tile >> 3, txi = tile & 7;  // 32 x 8 tiles of 4x16 outputs
  int ty0 = tyi * 4, tx0 = txi * 16;
  int h0 = ty0 >> 1, w0 = tx0 >> 1;     // input tile base (2 rows x 8 cols)

  const float* xb = x + (size_t)(n * CI + cg * 128) * HW;
  bool interior = (tyi >= 1) && (tyi <= 30) && (txi >= 1) && (txi <= 6);

  if (interior) {
#pragma unroll
    for (int j = 0; j < 9; ++j) {
      int f = tid + 256 * j;            // f4 index 0..2303 (128*18)
      int c = f / 18, rem = f - c * 18;
      int r = rem / 3, h = rem - r * 3;
      const float* gp = xb + (size_t)c * HW + (h0 - 2 + r) * WW + (w0 - 2 + h * 4);
      float2 lo = *(const float2*)(gp);
      float2 hi = *(const float2*)(gp + 2);
      *(float4*)(xpatch + c * 72 + r * 12 + h * 4) =
          make_float4(lo.x, lo.y, hi.x, hi.y);
    }
  } else {
#pragma unroll
    for (int j = 0; j < 9; ++j) {
      int f = tid + 256 * j;
      int c = f / 18, rem = f - c * 18;
      int r = rem / 3, h = rem - r * 3;
      int gh = h0 - 2 + r;
      float vv[4];
#pragma unroll
      for (int e = 0; e < 4; ++e) {
        int gw = w0 - 2 + h * 4 + e;
        vv[e] = (((unsigned)gh < 64u) && ((unsigned)gw < 64u))
                    ? xb[(size_t)c * HW + gh * WW + gw] : 0.f;
      }
      *(float4*)(xpatch + c * 72 + r * 12 + h * 4) =
          make_float4(vv[0], vv[1], vv[2], vv[3]);
    }
  }

  // Thread mapping: 16 channel-slots x 16 input pixels (2x8)
  int cslot = tid >> 4;                 // 0..15
  int ip = tid & 15;                    // py(1b) | px(3b)
  int py = ip >> 3, px = ip & 7;
  int oy0 = ty0 + py * 2, ox0 = tx0 + px * 2;
  int ysrc = h0 + py, xA = w0 + px;

  // Weight loads (issued before barrier; latency hides under staging drain).
  // 50 dwords via named uint4s -> elementwise into constant-indexed arrays.
  const unsigned int* wq0 =
      wpack + ((size_t)((n * 2 + 0) * HW) + ysrc * 64 + xA) * 28;
  const unsigned int* wq1 =
      wpack + ((size_t)((n * 2 + 1) * HW) + ysrc * 64 + xA) * 28;
  uint4 A0 = *(const uint4*)(wq0 + 0);
  uint4 A1 = *(const uint4*)(wq0 + 4);
  uint4 A2 = *(const uint4*)(wq0 + 8);
  uint4 A3 = *(const uint4*)(wq0 + 12);
  uint4 A4 = *(const uint4*)(wq0 + 16);
  uint4 A5 = *(const uint4*)(wq0 + 20);
  unsigned int A6 = wq0[24];
  uint4 B0 = *(const uint4*)(wq1 + 0);
  uint4 B1 = *(const uint4*)(wq1 + 4);
  uint4 B2 = *(const uint4*)(wq1 + 8);
  uint4 B3 = *(const uint4*)(wq1 + 12);
  uint4 B4 = *(const uint4*)(wq1 + 16);
  uint4 B5 = *(const uint4*)(wq1 + 20);
  unsigned int B6 = wq1[24];
  unsigned int wa[25] = {A0.x, A0.y, A0.z, A0.w, A1.x, A1.y, A1.z, A1.w,
                         A2.x, A2.y, A2.z, A2.w, A3.x, A3.y, A3.z, A3.w,
                         A4.x, A4.y, A4.z, A4.w, A5.x, A5.y, A5.z, A5.w, A6};
  unsigned int wb[25] = {B0.x, B0.y, B0.z, B0.w, B1.x, B1.y, B1.z, B1.w,
                         B2.x, B2.y, B2.z, B2.w, B3.x, B3.y, B3.z, B3.w,
                         B4.x, B4.y, B4.z, B4.w, B5.x, B5.y, B5.z, B5.w, B6};

  __syncthreads();

  float* outb = out + ((size_t)(n * CI + cg * 128) * HS + oy0) * WS_ + ox0;
  for (int it = 0; it < 8; ++it) {
    int cl = it * 16 + cslot;
    const float* p = xpatch + cl * 72 + py * 12 + px;
    float a00 = 0.f, a01 = 0.f, a10 = 0.f, a11 = 0.f;
#pragma unroll
    for (int i = 0; i < 5; ++i) {
      const float* row = p + i * 12;
      float g0 = row[0], g1 = row[1], g2 = row[2], g3 = row[3], g4 = row[4];
      float gg[5] = {g0, g1, g2, g3, g4};
#pragma unroll
      for (int j = 0; j < 5; ++j) {
        int k = i * 5 + j;
        unsigned int ua = wa[k], ub = wb[k];
        __half2 ha = *reinterpret_cast<__half2*>(&ua);
        __half2 hb = *reinterpret_cast<__half2*>(&ub);
        float fv = gg[j];
        a00 = fmaf(__half2float(__low2half(ha)),  fv, a00);
        a01 = fmaf(__half2float(__high2half(ha)), fv, a01);
        a10 = fmaf(__half2float(__low2half(hb)),  fv, a10);
        a11 = fmaf(__half2float(__high2half(hb)), fv, a11);
      }
    }
    float* ob = outb + (size_t)cl * HS * WS_;
    *(float2*)(ob)       = make_float2(a00, a01);
    *(float2*)(ob + WS_) = make_float2(a10, a11);
  }
}

// ---------------------------------------------------------------------------
extern "C" void kernel_launch(void* const* d_in, const int* in_sizes, int n_in,
                              void* d_out, int out_size, void* d_ws,
                              size_t ws_size, hipStream_t stream) {
  const float* x      = (const float*)d_in[0];
  const float* w_comp = (const float*)d_in[1];
  const float* b_comp = (const float*)d_in[2];
  const float* w_enc  = (const float*)d_in[3];
  const float* b_enc  = (const float*)d_in[4];
  float* out = (float*)d_out;

  char* ws = (char*)d_ws;
  unsigned short* comp_cl = (unsigned short*)ws;                  // 2,097,152 B
  unsigned short* Aw1     = (unsigned short*)(ws + 2097152);      //    32,768 B
  unsigned short* Aw2     = (unsigned short*)(ws + 2129920);      //   129,024 B
  unsigned int*   wpack   = (unsigned int*)(ws + 2359296);        // 3,670,016 B

  prep_kernel<<<dim3(316), 256, 0, stream>>>(w_comp, w_enc, Aw1, Aw2);
  conv1x1_mfma<<<dim3(256), 512, 0, stream>>>(x, Aw1, b_comp, comp_cl);
  kenc_mfma<<<dim3(256), 512, 0, stream>>>(comp_cl, Aw2, b_enc, wpack);
  reassembly_kernel<<<dim3(2048), 256, 0, stream>>>(x, wpack, out);
}

// Round 8
// 67.387 us; speedup vs baseline: 4.1003x; 4.1003x over previous
//
#include <hip/hip_runtime.h>
#include <hip/hip_fp16.h>

// Problem constants
#define NB 4      // batch
#define CI 256    // input channels
#define HH 64
#define WW 64
#define MC 64     // compressed channels
#define HS 128    // H*2
#define WS_ 128   // W*2
#define HW 4096   // HH*WW
// wpack: [n][sh:2][pix:4096][28] uints; each uint = half2 (q=2sh, q=2sh+1)

typedef __attribute__((ext_vector_type(8))) short short8v;   // 8 bf16 (4 VGPRs)
typedef __attribute__((ext_vector_type(4))) float floatx4;   // MFMA C/D

__device__ inline unsigned short f2bf(float f) {
  union { float f; unsigned u; } v; v.f = f;
  unsigned r = v.u + 0x7FFFu + ((v.u >> 16) & 1u);   // RNE
  return (unsigned short)(r >> 16);
}

// ---------------------------------------------------------------------------
// Prep: rearrange weights into MFMA A-fragment layout (bf16).
// ---------------------------------------------------------------------------
__global__ __launch_bounds__(256) void prep_kernel(
    const float* __restrict__ w_comp, const float* __restrict__ w_enc,
    unsigned short* __restrict__ Aw1, unsigned short* __restrict__ Aw2) {
  int i = blockIdx.x * 256 + threadIdx.x;
  if (i < 16384) {                       // 8*64*32
    int kl = i & 31, o = (i >> 5) & 63, ks = i >> 11;
    Aw1[i] = f2bf(w_comp[o * 256 + ks * 32 + kl]);
  } else if (i < 16384 + 64512) {        // 18*112*32
    int j = i - 16384;
    int kl = j & 31, o = (j >> 5) % 112, ks = (j >> 5) / 112;
    int t = ks >> 1, m = (ks & 1) * 32 + kl;
    Aw2[j] = (o < 100) ? f2bf(w_enc[o * 576 + m * 9 + t]) : (unsigned short)0;
  }
}

// ---------------------------------------------------------------------------
// Kernel 1: 1x1 conv via MFMA, K-split 2 (unchanged).
// ---------------------------------------------------------------------------
__global__ __launch_bounds__(512, 1) void conv1x1_mfma(
    const float* __restrict__ x, const unsigned short* __restrict__ Aw1,
    const float* __restrict__ b_comp, unsigned short* __restrict__ comp_cl) {
  __shared__ float pacc[4][64][17];
  int tid = threadIdx.x;
  int wid = tid >> 6, lane = tid & 63;
  int tileid = wid & 3, kh = wid >> 2;
  int Nt = blockIdx.x * 4 + tileid;       // 0..1023
  int n = Nt >> 8, pixbase = (Nt & 255) * 16;
  int l15 = lane & 15, g = lane >> 4;
  int pix = pixbase + l15;

  floatx4 acc[4];
#pragma unroll
  for (int ot = 0; ot < 4; ++ot) acc[ot] = (floatx4){0.f, 0.f, 0.f, 0.f};

  const float* xb = x + (size_t)n * CI * HW + pix;
  const unsigned short* ab = Aw1 + l15 * 32 + g * 8;

#pragma unroll
  for (int s = 0; s < 4; ++s) {
    int ks = kh * 4 + s;
    int c0 = ks * 32 + g * 8;
    short8v bfrag;
#pragma unroll
    for (int j = 0; j < 8; ++j)
      bfrag[j] = (short)f2bf(xb[(size_t)(c0 + j) * HW]);
#pragma unroll
    for (int ot = 0; ot < 4; ++ot) {
      short8v af = *(const short8v*)(ab + (ks * 64 + ot * 16) * 32);
      acc[ot] = __builtin_amdgcn_mfma_f32_16x16x32_bf16(af, bfrag, acc[ot], 0, 0, 0);
    }
  }

  if (kh == 1) {
#pragma unroll
    for (int ot = 0; ot < 4; ++ot)
#pragma unroll
      for (int r = 0; r < 4; ++r) pacc[tileid][lane][ot * 4 + r] = acc[ot][r];
  }
  __syncthreads();
  if (kh == 0) {
    unsigned short* cp = comp_cl + ((size_t)(n * HW + pix)) * 64;
#pragma unroll
    for (int ot = 0; ot < 4; ++ot) {
      const float4 bv = *(const float4*)(b_comp + ot * 16 + g * 4);
      float v0 = acc[ot][0] + pacc[tileid][lane][ot * 4 + 0] + bv.x;
      float v1 = acc[ot][1] + pacc[tileid][lane][ot * 4 + 1] + bv.y;
      float v2 = acc[ot][2] + pacc[tileid][lane][ot * 4 + 2] + bv.z;
      float v3 = acc[ot][3] + pacc[tileid][lane][ot * 4 + 3] + bv.w;
      unsigned h01 = (unsigned)f2bf(v0) | ((unsigned)f2bf(v1) << 16);
      unsigned h23 = (unsigned)f2bf(v2) | ((unsigned)f2bf(v3) << 16);
      *(int2*)(cp + ot * 16 + g * 4) = make_int2((int)h01, (int)h23);
    }
  }
}

// ---------------------------------------------------------------------------
// Kernel 2: 3x3 conv + pixel-shuffle + softmax(25), K-split 2 (unchanged).
// Packs f16 weight pairs: wpack[n][sh][pix][28], uint = half2(q=2sh, q=2sh+1).
// ---------------------------------------------------------------------------
__global__ __launch_bounds__(512, 1) void kenc_mfma(
    const unsigned short* __restrict__ comp_cl,
    const unsigned short* __restrict__ Aw2,
    const float* __restrict__ b_enc, unsigned int* __restrict__ wpack) {
  __shared__ float pacc[4][64][29];
  int tid = threadIdx.x;
  int wid = tid >> 6, lane = tid & 63;
  int tileid = wid & 3, kh = wid >> 2;
  int Nt = blockIdx.x * 4 + tileid;       // 0..1023
  int n = Nt >> 8, pixbase = (Nt & 255) * 16;
  int l15 = lane & 15, g = lane >> 4;
  int pix = pixbase + l15;
  int y = pix >> 6, xcol = pix & 63;

  bool vm[9];
  int sh9[9];
#pragma unroll
  for (int t = 0; t < 9; ++t) {
    int dy = t / 3, dx = t % 3;
    vm[t] = ((unsigned)(y + dy - 1) < 64u) && ((unsigned)(xcol + dx - 1) < 64u);
    sh9[t] = (dy - 1) * 64 + (dx - 1);
  }

  floatx4 acc[7];
#pragma unroll
  for (int ot = 0; ot < 7; ++ot) acc[ot] = (floatx4){0.f, 0.f, 0.f, 0.f};

  const unsigned short* cb = comp_cl + (size_t)n * HW * 64;
  const unsigned short* ab = Aw2 + l15 * 32 + g * 8;
  const short8v zv = {0, 0, 0, 0, 0, 0, 0, 0};

#pragma unroll
  for (int s = 0; s < 9; ++s) {
    int ks = kh * 9 + s;
    int t = ks >> 1, mh = ks & 1;
    const unsigned short* bp = cb + (pix + sh9[t]) * 64 + mh * 32 + g * 8;
    short8v bfrag = vm[t] ? *(const short8v*)bp : zv;
#pragma unroll
    for (int ot = 0; ot < 7; ++ot) {
      short8v af = *(const short8v*)(ab + (ks * 112 + ot * 16) * 32);
      acc[ot] = __builtin_amdgcn_mfma_f32_16x16x32_bf16(af, bfrag, acc[ot], 0, 0, 0);
    }
  }

  if (kh == 1) {
#pragma unroll
    for (int ot = 0; ot < 7; ++ot)
#pragma unroll
      for (int r = 0; r < 4; ++r) pacc[tileid][lane][ot * 4 + r] = acc[ot][r];
  }
  __syncthreads();
  if (kh == 0) {
#pragma unroll
    for (int ot = 0; ot < 7; ++ot) {
      int ob = ot * 16 + g * 4; if (ob > 96) ob = 96;
      const float4 bv = *(const float4*)(b_enc + ob);
      acc[ot][0] += pacc[tileid][lane][ot * 4 + 0] + bv.x;
      acc[ot][1] += pacc[tileid][lane][ot * 4 + 1] + bv.y;
      acc[ot][2] += pacc[tileid][lane][ot * 4 + 2] + bv.z;
      acc[ot][3] += pacc[tileid][lane][ot * 4 + 3] + bv.w;
    }

    // per-r softmax; write normalized values back into acc[ot][r]
#pragma unroll
    for (int r = 0; r < 4; ++r) {
      float m = acc[0][r];
#pragma unroll
      for (int ot = 1; ot < 6; ++ot) m = fmaxf(m, acc[ot][r]);
      if (g == 0) m = fmaxf(m, acc[6][r]);
      m = fmaxf(m, __shfl_xor(m, 16));
      m = fmaxf(m, __shfl_xor(m, 32));
      float s = 0.f;
      float e[7];
#pragma unroll
      for (int ot = 0; ot < 7; ++ot) {
        bool val = (ot < 6) || (g == 0);
        e[ot] = val ? __expf(acc[ot][r] - m) : 0.f;
        s += e[ot];
      }
      s += __shfl_xor(s, 16);
      s += __shfl_xor(s, 32);
      float inv = 1.f / s;
#pragma unroll
      for (int ot = 0; ot < 7; ++ot) acc[ot][r] = e[ot] * inv;
    }

    // pack f16 pairs and store: k = ot*4+g (valid k<25)
#pragma unroll
    for (int sh = 0; sh < 2; ++sh) {
      unsigned int* wq = wpack + ((size_t)((n * 2 + sh) * HW) + pix) * 28;
#pragma unroll
      for (int ot = 0; ot < 7; ++ot) {
        if ((ot < 6) || (g == 0)) {
          __half2 h2 = __floats2half2_rn(acc[ot][2 * sh], acc[ot][2 * sh + 1]);
          wq[ot * 4 + g] = *reinterpret_cast<unsigned int*>(&h2);
        }
      }
    }
  }
}

// ---------------------------------------------------------------------------
// Kernel 3: reassembly v7.
// Quad mapping (4 outputs of one input pixel share ONE 5x5 patch: 100 FMA
// per 25 LDS b32 reads). Weights stay PACKED f16 pairs in 50 NAMED uint4
// components (no arrays, no address-of -> no scratch; round 6/7 lesson) and
// are consumed directly by inline-asm v_fma_mix_f32 (op_sel picks the f16
// half) -> nothing for LICM to hoist, no unpack VALU.
// ---------------------------------------------------------------------------
#define TAP4(W, V, fv)                                                         \
  asm("v_fma_mix_f32 %0, %1, %2, %0 op_sel:[0,0,0] op_sel_hi:[1,0,0]"          \
      : "+v"(a00) : "v"(W), "v"(fv));                                          \
  asm("v_fma_mix_f32 %0, %1, %2, %0 op_sel:[1,0,0] op_sel_hi:[1,0,0]"          \
      : "+v"(a01) : "v"(W), "v"(fv));                                          \
  asm("v_fma_mix_f32 %0, %1, %2, %0 op_sel:[0,0,0] op_sel_hi:[1,0,0]"          \
      : "+v"(a10) : "v"(V), "v"(fv));                                          \
  asm("v_fma_mix_f32 %0, %1, %2, %0 op_sel:[1,0,0] op_sel_hi:[1,0,0]"          \
      : "+v"(a11) : "v"(V), "v"(fv));

__global__ __launch_bounds__(256, 4) void reassembly_kernel(
    const float* __restrict__ x, const unsigned int* __restrict__ wpack,
    float* __restrict__ out) {
  __shared__ float xpatch[128 * 72];    // [c][r:6][col:12]
  int tid = threadIdx.x;
  int bid = blockIdx.x;                 // tile(256) | n(4) | cg(2)
  int tile = bid & 255;
  int n = (bid >> 8) & 3;
  int cg = bid >> 10;
  int tyi = tile >> 3, txi = tile & 7;  // 32 x 8 tiles of 4x16 outputs
  int ty0 = tyi * 4, tx0 = txi * 16;
  int h0 = ty0 >> 1, w0 = tx0 >> 1;     // input tile base (2 rows x 8 cols)

  const float* xb = x + (size_t)(n * CI + cg * 128) * HW;
  bool interior = (tyi >= 1) && (tyi <= 30) && (txi >= 1) && (txi <= 6);

  if (interior) {
#pragma unroll
    for (int j = 0; j < 9; ++j) {
      int f = tid + 256 * j;            // f4 index 0..2303 (128*18)
      int c = f / 18, rem = f - c * 18;
      int r = rem / 3, h = rem - r * 3;
      const float* gp = xb + (size_t)c * HW + (h0 - 2 + r) * WW + (w0 - 2 + h * 4);
      float2 lo = *(const float2*)(gp);
      float2 hi = *(const float2*)(gp + 2);
      *(float4*)(xpatch + c * 72 + r * 12 + h * 4) =
          make_float4(lo.x, lo.y, hi.x, hi.y);
    }
  } else {
#pragma unroll
    for (int j = 0; j < 9; ++j) {
      int f = tid + 256 * j;
      int c = f / 18, rem = f - c * 18;
      int r = rem / 3, h = rem - r * 3;
      int gh = h0 - 2 + r;
      float vv[4];
#pragma unroll
      for (int e = 0; e < 4; ++e) {
        int gw = w0 - 2 + h * 4 + e;
        vv[e] = (((unsigned)gh < 64u) && ((unsigned)gw < 64u))
                    ? xb[(size_t)c * HW + gh * WW + gw] : 0.f;
      }
      *(float4*)(xpatch + c * 72 + r * 12 + h * 4) =
          make_float4(vv[0], vv[1], vv[2], vv[3]);
    }
  }

  // Thread mapping: 16 channel-slots x 16 input pixels (2x8)
  int cslot = tid >> 4;                 // 0..15
  int ip = tid & 15;                    // py(1b) | px(3b)
  int py = ip >> 3, px = ip & 7;
  int oy0 = ty0 + py * 2, ox0 = tx0 + px * 2;
  int ysrc = h0 + py, xA = w0 + px;

  // Weight loads (before barrier; latency hides under staging drain).
  // 50 packed dwords as named uint4 components -- never an array.
  const unsigned int* wq0 =
      wpack + ((size_t)((n * 2 + 0) * HW) + ysrc * 64 + xA) * 28;
  const unsigned int* wq1 =
      wpack + ((size_t)((n * 2 + 1) * HW) + ysrc * 64 + xA) * 28;
  uint4 A0 = *(const uint4*)(wq0 + 0);
  uint4 A1 = *(const uint4*)(wq0 + 4);
  uint4 A2 = *(const uint4*)(wq0 + 8);
  uint4 A3 = *(const uint4*)(wq0 + 12);
  uint4 A4 = *(const uint4*)(wq0 + 16);
  uint4 A5 = *(const uint4*)(wq0 + 20);
  unsigned int A6 = wq0[24];
  uint4 B0 = *(const uint4*)(wq1 + 0);
  uint4 B1 = *(const uint4*)(wq1 + 4);
  uint4 B2 = *(const uint4*)(wq1 + 8);
  uint4 B3 = *(const uint4*)(wq1 + 12);
  uint4 B4 = *(const uint4*)(wq1 + 16);
  uint4 B5 = *(const uint4*)(wq1 + 20);
  unsigned int B6 = wq1[24];

  __syncthreads();

  float* outb = out + ((size_t)(n * CI + cg * 128) * HS + oy0) * WS_ + ox0;
  for (int it = 0; it < 8; ++it) {
    int cl = it * 16 + cslot;
    const float* p = xpatch + cl * 72 + py * 12 + px;
    float a00 = 0.f, a01 = 0.f, a10 = 0.f, a11 = 0.f;
    {
      float g0 = p[0], g1 = p[1], g2 = p[2], g3 = p[3], g4 = p[4];
      TAP4(A0.x, B0.x, g0) TAP4(A0.y, B0.y, g1) TAP4(A0.z, B0.z, g2)
      TAP4(A0.w, B0.w, g3) TAP4(A1.x, B1.x, g4)
    }
    {
      const float* r1 = p + 12;
      float g0 = r1[0], g1 = r1[1], g2 = r1[2], g3 = r1[3], g4 = r1[4];
      TAP4(A1.y, B1.y, g0) TAP4(A1.z, B1.z, g1) TAP4(A1.w, B1.w, g2)
      TAP4(A2.x, B2.x, g3) TAP4(A2.y, B2.y, g4)
    }
    {
      const float* r2 = p + 24;
      float g0 = r2[0], g1 = r2[1], g2 = r2[2], g3 = r2[3], g4 = r2[4];
      TAP4(A2.z, B2.z, g0) TAP4(A2.w, B2.w, g1) TAP4(A3.x, B3.x, g2)
      TAP4(A3.y, B3.y, g3) TAP4(A3.z, B3.z, g4)
    }
    {
      const float* r3 = p + 36;
      float g0 = r3[0], g1 = r3[1], g2 = r3[2], g3 = r3[3], g4 = r3[4];
      TAP4(A3.w, B3.w, g0) TAP4(A4.x, B4.x, g1) TAP4(A4.y, B4.y, g2)
      TAP4(A4.z, B4.z, g3) TAP4(A4.w, B4.w, g4)
    }
    {
      const float* r4 = p + 48;
      float g0 = r4[0], g1 = r4[1], g2 = r4[2], g3 = r4[3], g4 = r4[4];
      TAP4(A5.x, B5.x, g0) TAP4(A5.y, B5.y, g1) TAP4(A5.z, B5.z, g2)
      TAP4(A5.w, B5.w, g3) TAP4(A6,   B6,   g4)
    }
    float* ob = outb + (size_t)cl * HS * WS_;
    *(float2*)(ob)       = make_float2(a00, a01);
    *(float2*)(ob + WS_) = make_float2(a10, a11);
  }
}

// ---------------------------------------------------------------------------
extern "C" void kernel_launch(void* const* d_in, const int* in_sizes, int n_in,
                              void* d_out, int out_size, void* d_ws,
                              size_t ws_size, hipStream_t stream) {
  const float* x      = (const float*)d_in[0];
  const float* w_comp = (const float*)d_in[1];
  const float* b_comp = (const float*)d_in[2];
  const float* w_enc  = (const float*)d_in[3];
  const float* b_enc  = (const float*)d_in[4];
  float* out = (float*)d_out;

  char* ws = (char*)d_ws;
  unsigned short* comp_cl = (unsigned short*)ws;                  // 2,097,152 B
  unsigned short* Aw1     = (unsigned short*)(ws + 2097152);      //    32,768 B
  unsigned short* Aw2     = (unsigned short*)(ws + 2129920);      //   129,024 B
  unsigned int*   wpack   = (unsigned int*)(ws + 2359296);        // 3,670,016 B

  prep_kernel<<<dim3(316), 256, 0, stream>>>(w_comp, w_enc, Aw1, Aw2);
  conv1x1_mfma<<<dim3(256), 512, 0, stream>>>(x, Aw1, b_comp, comp_cl);
  kenc_mfma<<<dim3(256), 512, 0, stream>>>(comp_cl, Aw2, b_enc, wpack);
  reassembly_kernel<<<dim3(2048), 256, 0, stream>>>(x, wpack, out);
}

// Round 9
// 66.120 us; speedup vs baseline: 4.1789x; 1.0192x over previous
//
#include <hip/hip_runtime.h>
#include <hip/hip_fp16.h>

// Problem constants
#define NB 4      // batch
#define CI 256    // input channels
#define HH 64
#define WW 64
#define MC 64     // compressed channels
#define HS 128    // H*2
#define WS_ 128   // W*2
#define HW 4096   // HH*WW
// wpack: [n][sh:2][pix:4096][28] uints; each uint = half2 (q=2sh, q=2sh+1)

typedef __attribute__((ext_vector_type(8))) short short8v;   // 8 bf16 (4 VGPRs)
typedef __attribute__((ext_vector_type(4))) float floatx4;   // MFMA C/D

__device__ inline unsigned short f2bf(float f) {
  union { float f; unsigned u; } v; v.f = f;
  unsigned r = v.u + 0x7FFFu + ((v.u >> 16) & 1u);   // RNE
  return (unsigned short)(r >> 16);
}

// ---------------------------------------------------------------------------
// Prep: rearrange weights into MFMA A-fragment layout (bf16).
// ---------------------------------------------------------------------------
__global__ __launch_bounds__(256) void prep_kernel(
    const float* __restrict__ w_comp, const float* __restrict__ w_enc,
    unsigned short* __restrict__ Aw1, unsigned short* __restrict__ Aw2) {
  int i = blockIdx.x * 256 + threadIdx.x;
  if (i < 16384) {                       // 8*64*32
    int kl = i & 31, o = (i >> 5) & 63, ks = i >> 11;
    Aw1[i] = f2bf(w_comp[o * 256 + ks * 32 + kl]);
  } else if (i < 16384 + 64512) {        // 18*112*32
    int j = i - 16384;
    int kl = j & 31, o = (j >> 5) % 112, ks = (j >> 5) / 112;
    int t = ks >> 1, m = (ks & 1) * 32 + kl;
    Aw2[j] = (o < 100) ? f2bf(w_enc[o * 576 + m * 9 + t]) : (unsigned short)0;
  }
}

// ---------------------------------------------------------------------------
// Kernel 1: 1x1 conv via MFMA, K-split 4 (kh owns 64 channels = 2 k-steps).
// Block = 512 thr = 8 waves: 2 pixel-tiles x 4 kh. Grid 512 -> 4096 waves
// = 16 waves/CU. Partials via pacc (stride 49); kh==0 reduces 3 + bias.
// ---------------------------------------------------------------------------
__global__ __launch_bounds__(512, 1) void conv1x1_mfma(
    const float* __restrict__ x, const unsigned short* __restrict__ Aw1,
    const float* __restrict__ b_comp, unsigned short* __restrict__ comp_cl) {
  __shared__ float pacc[2][64][49];
  int tid = threadIdx.x;
  int wid = tid >> 6, lane = tid & 63;
  int tileid = wid & 1, kh = wid >> 1;    // kh 0..3
  int Nt = blockIdx.x * 2 + tileid;       // 0..1023
  int n = Nt >> 8, pixbase = (Nt & 255) * 16;
  int l15 = lane & 15, g = lane >> 4;
  int pix = pixbase + l15;

  floatx4 acc[4];
#pragma unroll
  for (int ot = 0; ot < 4; ++ot) acc[ot] = (floatx4){0.f, 0.f, 0.f, 0.f};

  const float* xb = x + (size_t)n * CI * HW + pix;
  const unsigned short* ab = Aw1 + l15 * 32 + g * 8;

#pragma unroll
  for (int s = 0; s < 2; ++s) {
    int ks = kh * 2 + s;
    int c0 = ks * 32 + g * 8;
    short8v bfrag;
#pragma unroll
    for (int j = 0; j < 8; ++j)
      bfrag[j] = (short)f2bf(xb[(size_t)(c0 + j) * HW]);
#pragma unroll
    for (int ot = 0; ot < 4; ++ot) {
      short8v af = *(const short8v*)(ab + (ks * 64 + ot * 16) * 32);
      acc[ot] = __builtin_amdgcn_mfma_f32_16x16x32_bf16(af, bfrag, acc[ot], 0, 0, 0);
    }
  }

  if (kh > 0) {
#pragma unroll
    for (int ot = 0; ot < 4; ++ot)
#pragma unroll
      for (int r = 0; r < 4; ++r)
        pacc[tileid][lane][(kh - 1) * 16 + ot * 4 + r] = acc[ot][r];
  }
  __syncthreads();
  if (kh == 0) {
    unsigned short* cp = comp_cl + ((size_t)(n * HW + pix)) * 64;
#pragma unroll
    for (int ot = 0; ot < 4; ++ot) {
      const float4 bv = *(const float4*)(b_comp + ot * 16 + g * 4);
      float v0 = acc[ot][0] + bv.x, v1 = acc[ot][1] + bv.y;
      float v2 = acc[ot][2] + bv.z, v3 = acc[ot][3] + bv.w;
#pragma unroll
      for (int sl = 0; sl < 3; ++sl) {
        v0 += pacc[tileid][lane][sl * 16 + ot * 4 + 0];
        v1 += pacc[tileid][lane][sl * 16 + ot * 4 + 1];
        v2 += pacc[tileid][lane][sl * 16 + ot * 4 + 2];
        v3 += pacc[tileid][lane][sl * 16 + ot * 4 + 3];
      }
      unsigned h01 = (unsigned)f2bf(v0) | ((unsigned)f2bf(v1) << 16);
      unsigned h23 = (unsigned)f2bf(v2) | ((unsigned)f2bf(v3) << 16);
      *(int2*)(cp + ot * 16 + g * 4) = make_int2((int)h01, (int)h23);
    }
  }
}

// ---------------------------------------------------------------------------
// Kernel 2: 3x3 conv + pixel-shuffle + softmax(25), K-split 4 (5/5/4/4 ks).
// Block = 512 thr = 8 waves: 2 pixel-tiles x 4 kh. Grid 512 -> 16 waves/CU.
// pacc stride 85 (3 slots x 28 + pad). kh==0 reduces + softmax + f16-pack.
// ---------------------------------------------------------------------------
__global__ __launch_bounds__(512, 1) void kenc_mfma(
    const unsigned short* __restrict__ comp_cl,
    const unsigned short* __restrict__ Aw2,
    const float* __restrict__ b_enc, unsigned int* __restrict__ wpack) {
  __shared__ float pacc[2][64][85];
  int tid = threadIdx.x;
  int wid = tid >> 6, lane = tid & 63;
  int tileid = wid & 1, kh = wid >> 1;    // kh 0..3
  int Nt = blockIdx.x * 2 + tileid;       // 0..1023
  int n = Nt >> 8, pixbase = (Nt & 255) * 16;
  int l15 = lane & 15, g = lane >> 4;
  int pix = pixbase + l15;
  int y = pix >> 6, xcol = pix & 63;

  bool vm[9];
  int sh9[9];
#pragma unroll
  for (int t = 0; t < 9; ++t) {
    int dy = t / 3, dx = t % 3;
    vm[t] = ((unsigned)(y + dy - 1) < 64u) && ((unsigned)(xcol + dx - 1) < 64u);
    sh9[t] = (dy - 1) * 64 + (dx - 1);
  }

  floatx4 acc[7];
#pragma unroll
  for (int ot = 0; ot < 7; ++ot) acc[ot] = (floatx4){0.f, 0.f, 0.f, 0.f};

  const unsigned short* cb = comp_cl + (size_t)n * HW * 64;
  const unsigned short* ab = Aw2 + l15 * 32 + g * 8;
  const short8v zv = {0, 0, 0, 0, 0, 0, 0, 0};

  int ks0 = (kh < 2) ? kh * 5 : 10 + (kh - 2) * 4;
  int len = (kh < 2) ? 5 : 4;
#pragma unroll
  for (int s = 0; s < 5; ++s) {
    if (s < len) {
      int ks = ks0 + s;
      int t = ks >> 1, mh = ks & 1;
      const unsigned short* bp = cb + (pix + sh9[t]) * 64 + mh * 32 + g * 8;
      short8v bfrag = vm[t] ? *(const short8v*)bp : zv;
#pragma unroll
      for (int ot = 0; ot < 7; ++ot) {
        short8v af = *(const short8v*)(ab + (ks * 112 + ot * 16) * 32);
        acc[ot] = __builtin_amdgcn_mfma_f32_16x16x32_bf16(af, bfrag, acc[ot], 0, 0, 0);
      }
    }
  }

  if (kh > 0) {
#pragma unroll
    for (int ot = 0; ot < 7; ++ot)
#pragma unroll
      for (int r = 0; r < 4; ++r)
        pacc[tileid][lane][(kh - 1) * 28 + ot * 4 + r] = acc[ot][r];
  }
  __syncthreads();
  if (kh == 0) {
#pragma unroll
    for (int ot = 0; ot < 7; ++ot) {
      int ob = ot * 16 + g * 4; if (ob > 96) ob = 96;
      const float4 bv = *(const float4*)(b_enc + ob);
      acc[ot][0] += bv.x; acc[ot][1] += bv.y;
      acc[ot][2] += bv.z; acc[ot][3] += bv.w;
#pragma unroll
      for (int sl = 0; sl < 3; ++sl) {
        acc[ot][0] += pacc[tileid][lane][sl * 28 + ot * 4 + 0];
        acc[ot][1] += pacc[tileid][lane][sl * 28 + ot * 4 + 1];
        acc[ot][2] += pacc[tileid][lane][sl * 28 + ot * 4 + 2];
        acc[ot][3] += pacc[tileid][lane][sl * 28 + ot * 4 + 3];
      }
    }

    // per-r softmax; normalized values back into acc[ot][r]
#pragma unroll
    for (int r = 0; r < 4; ++r) {
      float m = acc[0][r];
#pragma unroll
      for (int ot = 1; ot < 6; ++ot) m = fmaxf(m, acc[ot][r]);
      if (g == 0) m = fmaxf(m, acc[6][r]);
      m = fmaxf(m, __shfl_xor(m, 16));
      m = fmaxf(m, __shfl_xor(m, 32));
      float s = 0.f;
      float e[7];
#pragma unroll
      for (int ot = 0; ot < 7; ++ot) {
        bool val = (ot < 6) || (g == 0);
        e[ot] = val ? __expf(acc[ot][r] - m) : 0.f;
        s += e[ot];
      }
      s += __shfl_xor(s, 16);
      s += __shfl_xor(s, 32);
      float inv = 1.f / s;
#pragma unroll
      for (int ot = 0; ot < 7; ++ot) acc[ot][r] = e[ot] * inv;
    }

    // pack f16 pairs and store: k = ot*4+g (valid k<25)
#pragma unroll
    for (int sh = 0; sh < 2; ++sh) {
      unsigned int* wq = wpack + ((size_t)((n * 2 + sh) * HW) + pix) * 28;
#pragma unroll
      for (int ot = 0; ot < 7; ++ot) {
        if ((ot < 6) || (g == 0)) {
          __half2 h2 = __floats2half2_rn(acc[ot][2 * sh], acc[ot][2 * sh + 1]);
          wq[ot * 4 + g] = *reinterpret_cast<unsigned int*>(&h2);
        }
      }
    }
  }
}

// ---------------------------------------------------------------------------
// Kernel 3: reassembly v8 = v7 + T14 2-stage channel pipeline.
// Stage s covers 64 channels; LDS double-buffered 2 x 64x72 f32 = 36.9 KB.
// Stage-1 global loads issue BEFORE stage-0 compute (latency hides under
// 400 fma_mix). Weights = 50 packed f16-pair dwords in named uint4s,
// consumed by inline-asm v_fma_mix_f32 (r7 pattern, scratch-free).
// ---------------------------------------------------------------------------
#define TAP4(W, V, fv)                                                         \
  asm("v_fma_mix_f32 %0, %1, %2, %0 op_sel:[0,0,0] op_sel_hi:[1,0,0]"          \
      : "+v"(a00) : "v"(W), "v"(fv));                                          \
  asm("v_fma_mix_f32 %0, %1, %2, %0 op_sel:[1,0,0] op_sel_hi:[1,0,0]"          \
      : "+v"(a01) : "v"(W), "v"(fv));                                          \
  asm("v_fma_mix_f32 %0, %1, %2, %0 op_sel:[0,0,0] op_sel_hi:[1,0,0]"          \
      : "+v"(a10) : "v"(V), "v"(fv));                                          \
  asm("v_fma_mix_f32 %0, %1, %2, %0 op_sel:[1,0,0] op_sel_hi:[1,0,0]"          \
      : "+v"(a11) : "v"(V), "v"(fv));

#define ROW5(WA, WB, WC, WD, WE, VA, VB, VC, VD, VE, RP)                       \
  { const float* rr = (RP);                                                    \
    float g0 = rr[0], g1 = rr[1], g2 = rr[2], g3 = rr[3], g4 = rr[4];          \
    TAP4(WA, VA, g0) TAP4(WB, VB, g1) TAP4(WC, VC, g2)                         \
    TAP4(WD, VD, g3) TAP4(WE, VE, g4) }

#define COMPUTE_STAGE(BUFP, CB)                                                \
  for (int it = 0; it < 4; ++it) {                                             \
    int cl = it * 16 + cslot;                                                  \
    const float* p = (BUFP) + cl * 72 + py * 12 + px;                          \
    float a00 = 0.f, a01 = 0.f, a10 = 0.f, a11 = 0.f;                          \
    ROW5(A0.x, A0.y, A0.z, A0.w, A1.x, B0.x, B0.y, B0.z, B0.w, B1.x, p)        \
    ROW5(A1.y, A1.z, A1.w, A2.x, A2.y, B1.y, B1.z, B1.w, B2.x, B2.y, p + 12)   \
    ROW5(A2.z, A2.w, A3.x, A3.y, A3.z, B2.z, B2.w, B3.x, B3.y, B3.z, p + 24)   \
    ROW5(A3.w, A4.x, A4.y, A4.z, A4.w, B3.w, B4.x, B4.y, B4.z, B4.w, p + 36)   \
    ROW5(A5.x, A5.y, A5.z, A5.w, A6,   B5.x, B5.y, B5.z, B5.w, B6,   p + 48)   \
    float* ob = outb + (size_t)((CB) + cl) * HS * WS_;                         \
    *(float2*)(ob)       = make_float2(a00, a01);                              \
    *(float2*)(ob + WS_) = make_float2(a10, a11);                              \
  }

__device__ __forceinline__ float4 load_slot(const float* __restrict__ xb,
                                            int h0, int w0, int f,
                                            bool interior) {
  int c = f / 18, rem = f - c * 18, r = rem / 3, h = rem - r * 3;
  int gh = h0 - 2 + r, gw = w0 - 2 + h * 4;
  if (interior) {
    const float* gp = xb + (size_t)c * HW + gh * WW + gw;
    float2 lo = *(const float2*)gp;
    float2 hi = *(const float2*)(gp + 2);
    return make_float4(lo.x, lo.y, hi.x, hi.y);
  }
  float v0 = 0.f, v1 = 0.f, v2 = 0.f, v3 = 0.f;
  if ((unsigned)gh < 64u) {
    const float* rowp = xb + (size_t)c * HW + gh * WW;
    if ((unsigned)(gw + 0) < 64u) v0 = rowp[gw + 0];
    if ((unsigned)(gw + 1) < 64u) v1 = rowp[gw + 1];
    if ((unsigned)(gw + 2) < 64u) v2 = rowp[gw + 2];
    if ((unsigned)(gw + 3) < 64u) v3 = rowp[gw + 3];
  }
  return make_float4(v0, v1, v2, v3);
}

__global__ __launch_bounds__(256, 4) void reassembly_kernel(
    const float* __restrict__ x, const unsigned int* __restrict__ wpack,
    float* __restrict__ out) {
  __shared__ float xp[2][64 * 72];      // double-buffered 64-ch stages
  int tid = threadIdx.x;
  int bid = blockIdx.x;                 // tile(256) | n(4) | cg(2)
  int tile = bid & 255;
  int n = (bid >> 8) & 3;
  int cg = bid >> 10;
  int tyi = tile >> 3, txi = tile & 7;  // 32 x 8 tiles of 4x16 outputs
  int ty0 = tyi * 4, tx0 = txi * 16;
  int h0 = ty0 >> 1, w0 = tx0 >> 1;     // input tile base (2 rows x 8 cols)

  const float* xb0 = x + (size_t)(n * CI + cg * 128) * HW;        // stage 0
  const float* xb1 = xb0 + (size_t)64 * HW;                       // stage 1
  bool interior = (tyi >= 1) && (tyi <= 30) && (txi >= 1) && (txi <= 6);
  bool half = tid < 128;
  int f4 = 1024 + tid;                  // j==4 slot (tid<128 only)

  // ---- stage 0: load + LDS write (direct)
  {
    float4 s0 = load_slot(xb0, h0, w0, tid, interior);
    float4 s1 = load_slot(xb0, h0, w0, tid + 256, interior);
    float4 s2 = load_slot(xb0, h0, w0, tid + 512, interior);
    float4 s3 = load_slot(xb0, h0, w0, tid + 768, interior);
    *(float4*)(xp[0] + ((tid)       / 18) * 72 + ((tid)       % 18) * 4) = s0;
    *(float4*)(xp[0] + ((tid + 256) / 18) * 72 + ((tid + 256) % 18) * 4) = s1;
    *(float4*)(xp[0] + ((tid + 512) / 18) * 72 + ((tid + 512) % 18) * 4) = s2;
    *(float4*)(xp[0] + ((tid + 768) / 18) * 72 + ((tid + 768) % 18) * 4) = s3;
    if (half) {
      float4 s4 = load_slot(xb0, h0, w0, f4, interior);
      *(float4*)(xp[0] + (f4 / 18) * 72 + (f4 % 18) * 4) = s4;
    }
  }

  // thread mapping + weight loads (latency hides under barrier drain)
  int cslot = tid >> 4;                 // 0..15
  int ip = tid & 15;                    // py(1b) | px(3b)
  int py = ip >> 3, px = ip & 7;
  int oy0 = ty0 + py * 2, ox0 = tx0 + px * 2;
  int ysrc = h0 + py, xA = w0 + px;

  const unsigned int* wq0 =
      wpack + ((size_t)((n * 2 + 0) * HW) + ysrc * 64 + xA) * 28;
  const unsigned int* wq1 =
      wpack + ((size_t)((n * 2 + 1) * HW) + ysrc * 64 + xA) * 28;
  uint4 A0 = *(const uint4*)(wq0 + 0);
  uint4 A1 = *(const uint4*)(wq0 + 4);
  uint4 A2 = *(const uint4*)(wq0 + 8);
  uint4 A3 = *(const uint4*)(wq0 + 12);
  uint4 A4 = *(const uint4*)(wq0 + 16);
  uint4 A5 = *(const uint4*)(wq0 + 20);
  unsigned int A6 = wq0[24];
  uint4 B0 = *(const uint4*)(wq1 + 0);
  uint4 B1 = *(const uint4*)(wq1 + 4);
  uint4 B2 = *(const uint4*)(wq1 + 8);
  uint4 B3 = *(const uint4*)(wq1 + 12);
  uint4 B4 = *(const uint4*)(wq1 + 16);
  uint4 B5 = *(const uint4*)(wq1 + 20);
  unsigned int B6 = wq1[24];

  __syncthreads();

  // ---- stage 1: issue loads NOW (land during stage-0 compute)
  float4 t0 = load_slot(xb1, h0, w0, tid, interior);
  float4 t1 = load_slot(xb1, h0, w0, tid + 256, interior);
  float4 t2 = load_slot(xb1, h0, w0, tid + 512, interior);
  float4 t3 = load_slot(xb1, h0, w0, tid + 768, interior);
  float4 t4 = half ? load_slot(xb1, h0, w0, f4, interior)
                   : make_float4(0.f, 0.f, 0.f, 0.f);

  float* outb = out + ((size_t)(n * CI + cg * 128) * HS + oy0) * WS_ + ox0;

  // ---- compute stage 0 (channels 0..63 of this cg)
  COMPUTE_STAGE(xp[0], 0)

  // ---- write stage 1 to LDS, barrier, compute
  *(float4*)(xp[1] + ((tid)       / 18) * 72 + ((tid)       % 18) * 4) = t0;
  *(float4*)(xp[1] + ((tid + 256) / 18) * 72 + ((tid + 256) % 18) * 4) = t1;
  *(float4*)(xp[1] + ((tid + 512) / 18) * 72 + ((tid + 512) % 18) * 4) = t2;
  *(float4*)(xp[1] + ((tid + 768) / 18) * 72 + ((tid + 768) % 18) * 4) = t3;
  if (half)
    *(float4*)(xp[1] + (f4 / 18) * 72 + (f4 % 18) * 4) = t4;
  __syncthreads();

  COMPUTE_STAGE(xp[1], 64)
}

// ---------------------------------------------------------------------------
extern "C" void kernel_launch(void* const* d_in, const int* in_sizes, int n_in,
                              void* d_out, int out_size, void* d_ws,
                              size_t ws_size, hipStream_t stream) {
  const float* x      = (const float*)d_in[0];
  const float* w_comp = (const float*)d_in[1];
  const float* b_comp = (const float*)d_in[2];
  const float* w_enc  = (const float*)d_in[3];
  const float* b_enc  = (const float*)d_in[4];
  float* out = (float*)d_out;

  char* ws = (char*)d_ws;
  unsigned short* comp_cl = (unsigned short*)ws;                  // 2,097,152 B
  unsigned short* Aw1     = (unsigned short*)(ws + 2097152);      //    32,768 B
  unsigned short* Aw2     = (unsigned short*)(ws + 2129920);      //   129,024 B
  unsigned int*   wpack   = (unsigned int*)(ws + 2359296);        // 3,670,016 B

  prep_kernel<<<dim3(316), 256, 0, stream>>>(w_comp, w_enc, Aw1, Aw2);
  conv1x1_mfma<<<dim3(512), 512, 0, stream>>>(x, Aw1, b_comp, comp_cl);
  kenc_mfma<<<dim3(512), 512, 0, stream>>>(comp_cl, Aw2, b_enc, wpack);
  reassembly_kernel<<<dim3(2048), 256, 0, stream>>>(x, wpack, out);
}

// Round 10
// 65.140 us; speedup vs baseline: 4.2418x; 1.0150x over previous
//
#include <hip/hip_runtime.h>
#include <hip/hip_fp16.h>

// Problem constants
#define NB 4      // batch
#define CI 256    // input channels
#define HH 64
#define WW 64
#define MC 64     // compressed channels
#define HS 128    // H*2
#define WS_ 128   // W*2
#define HW 4096   // HH*WW
// wpack: [n][sh:2][pix:4096][28] uints; each uint = half2 (q=2sh, q=2sh+1)

typedef __attribute__((ext_vector_type(8))) short short8v;   // 8 bf16 (4 VGPRs)
typedef __attribute__((ext_vector_type(4))) float floatx4;   // MFMA C/D

__device__ inline unsigned short f2bf(float f) {
  union { float f; unsigned u; } v; v.f = f;
  unsigned r = v.u + 0x7FFFu + ((v.u >> 16) & 1u);   // RNE
  return (unsigned short)(r >> 16);
}

// ---------------------------------------------------------------------------
// Prep: rearrange weights into MFMA A-fragment layout (bf16).  (unchanged)
// ---------------------------------------------------------------------------
__global__ __launch_bounds__(256) void prep_kernel(
    const float* __restrict__ w_comp, const float* __restrict__ w_enc,
    unsigned short* __restrict__ Aw1, unsigned short* __restrict__ Aw2) {
  int i = blockIdx.x * 256 + threadIdx.x;
  if (i < 16384) {                       // 8*64*32
    int kl = i & 31, o = (i >> 5) & 63, ks = i >> 11;
    Aw1[i] = f2bf(w_comp[o * 256 + ks * 32 + kl]);
  } else if (i < 16384 + 64512) {        // 18*112*32
    int j = i - 16384;
    int kl = j & 31, o = (j >> 5) % 112, ks = (j >> 5) / 112;
    int t = ks >> 1, m = (ks & 1) * 32 + kl;
    Aw2[j] = (o < 100) ? f2bf(w_enc[o * 576 + m * 9 + t]) : (unsigned short)0;
  }
}

// ---------------------------------------------------------------------------
// Kernel 1: 1x1 conv via MFMA, K-split 4 (unchanged from round 9).
// ---------------------------------------------------------------------------
__global__ __launch_bounds__(512, 1) void conv1x1_mfma(
    const float* __restrict__ x, const unsigned short* __restrict__ Aw1,
    const float* __restrict__ b_comp, unsigned short* __restrict__ comp_cl) {
  __shared__ float pacc[2][64][49];
  int tid = threadIdx.x;
  int wid = tid >> 6, lane = tid & 63;
  int tileid = wid & 1, kh = wid >> 1;    // kh 0..3
  int Nt = blockIdx.x * 2 + tileid;       // 0..1023
  int n = Nt >> 8, pixbase = (Nt & 255) * 16;
  int l15 = lane & 15, g = lane >> 4;
  int pix = pixbase + l15;

  floatx4 acc[4];
#pragma unroll
  for (int ot = 0; ot < 4; ++ot) acc[ot] = (floatx4){0.f, 0.f, 0.f, 0.f};

  const float* xb = x + (size_t)n * CI * HW + pix;
  const unsigned short* ab = Aw1 + l15 * 32 + g * 8;

#pragma unroll
  for (int s = 0; s < 2; ++s) {
    int ks = kh * 2 + s;
    int c0 = ks * 32 + g * 8;
    short8v bfrag;
#pragma unroll
    for (int j = 0; j < 8; ++j)
      bfrag[j] = (short)f2bf(xb[(size_t)(c0 + j) * HW]);
#pragma unroll
    for (int ot = 0; ot < 4; ++ot) {
      short8v af = *(const short8v*)(ab + (ks * 64 + ot * 16) * 32);
      acc[ot] = __builtin_amdgcn_mfma_f32_16x16x32_bf16(af, bfrag, acc[ot], 0, 0, 0);
    }
  }

  if (kh > 0) {
#pragma unroll
    for (int ot = 0; ot < 4; ++ot)
#pragma unroll
      for (int r = 0; r < 4; ++r)
        pacc[tileid][lane][(kh - 1) * 16 + ot * 4 + r] = acc[ot][r];
  }
  __syncthreads();
  if (kh == 0) {
    unsigned short* cp = comp_cl + ((size_t)(n * HW + pix)) * 64;
#pragma unroll
    for (int ot = 0; ot < 4; ++ot) {
      const float4 bv = *(const float4*)(b_comp + ot * 16 + g * 4);
      float v0 = acc[ot][0] + bv.x, v1 = acc[ot][1] + bv.y;
      float v2 = acc[ot][2] + bv.z, v3 = acc[ot][3] + bv.w;
#pragma unroll
      for (int sl = 0; sl < 3; ++sl) {
        v0 += pacc[tileid][lane][sl * 16 + ot * 4 + 0];
        v1 += pacc[tileid][lane][sl * 16 + ot * 4 + 1];
        v2 += pacc[tileid][lane][sl * 16 + ot * 4 + 2];
        v3 += pacc[tileid][lane][sl * 16 + ot * 4 + 3];
      }
      unsigned h01 = (unsigned)f2bf(v0) | ((unsigned)f2bf(v1) << 16);
      unsigned h23 = (unsigned)f2bf(v2) | ((unsigned)f2bf(v3) << 16);
      *(int2*)(cp + ot * 16 + g * 4) = make_int2((int)h01, (int)h23);
    }
  }
}

// ---------------------------------------------------------------------------
// Kernel 2: 3x3 conv + pixel-shuffle + softmax(25), K-split 4 (unchanged).
// ---------------------------------------------------------------------------
__global__ __launch_bounds__(512, 1) void kenc_mfma(
    const unsigned short* __restrict__ comp_cl,
    const unsigned short* __restrict__ Aw2,
    const float* __restrict__ b_enc, unsigned int* __restrict__ wpack) {
  __shared__ float pacc[2][64][85];
  int tid = threadIdx.x;
  int wid = tid >> 6, lane = tid & 63;
  int tileid = wid & 1, kh = wid >> 1;    // kh 0..3
  int Nt = blockIdx.x * 2 + tileid;       // 0..1023
  int n = Nt >> 8, pixbase = (Nt & 255) * 16;
  int l15 = lane & 15, g = lane >> 4;
  int pix = pixbase + l15;
  int y = pix >> 6, xcol = pix & 63;

  bool vm[9];
  int sh9[9];
#pragma unroll
  for (int t = 0; t < 9; ++t) {
    int dy = t / 3, dx = t % 3;
    vm[t] = ((unsigned)(y + dy - 1) < 64u) && ((unsigned)(xcol + dx - 1) < 64u);
    sh9[t] = (dy - 1) * 64 + (dx - 1);
  }

  floatx4 acc[7];
#pragma unroll
  for (int ot = 0; ot < 7; ++ot) acc[ot] = (floatx4){0.f, 0.f, 0.f, 0.f};

  const unsigned short* cb = comp_cl + (size_t)n * HW * 64;
  const unsigned short* ab = Aw2 + l15 * 32 + g * 8;
  const short8v zv = {0, 0, 0, 0, 0, 0, 0, 0};

  int ks0 = (kh < 2) ? kh * 5 : 10 + (kh - 2) * 4;
  int len = (kh < 2) ? 5 : 4;
#pragma unroll
  for (int s = 0; s < 5; ++s) {
    if (s < len) {
      int ks = ks0 + s;
      int t = ks >> 1, mh = ks & 1;
      const unsigned short* bp = cb + (pix + sh9[t]) * 64 + mh * 32 + g * 8;
      short8v bfrag = vm[t] ? *(const short8v*)bp : zv;
#pragma unroll
      for (int ot = 0; ot < 7; ++ot) {
        short8v af = *(const short8v*)(ab + (ks * 112 + ot * 16) * 32);
        acc[ot] = __builtin_amdgcn_mfma_f32_16x16x32_bf16(af, bfrag, acc[ot], 0, 0, 0);
      }
    }
  }

  if (kh > 0) {
#pragma unroll
    for (int ot = 0; ot < 7; ++ot)
#pragma unroll
      for (int r = 0; r < 4; ++r)
        pacc[tileid][lane][(kh - 1) * 28 + ot * 4 + r] = acc[ot][r];
  }
  __syncthreads();
  if (kh == 0) {
#pragma unroll
    for (int ot = 0; ot < 7; ++ot) {
      int ob = ot * 16 + g * 4; if (ob > 96) ob = 96;
      const float4 bv = *(const float4*)(b_enc + ob);
      acc[ot][0] += bv.x; acc[ot][1] += bv.y;
      acc[ot][2] += bv.z; acc[ot][3] += bv.w;
#pragma unroll
      for (int sl = 0; sl < 3; ++sl) {
        acc[ot][0] += pacc[tileid][lane][sl * 28 + ot * 4 + 0];
        acc[ot][1] += pacc[tileid][lane][sl * 28 + ot * 4 + 1];
        acc[ot][2] += pacc[tileid][lane][sl * 28 + ot * 4 + 2];
        acc[ot][3] += pacc[tileid][lane][sl * 28 + ot * 4 + 3];
      }
    }

#pragma unroll
    for (int r = 0; r < 4; ++r) {
      float m = acc[0][r];
#pragma unroll
      for (int ot = 1; ot < 6; ++ot) m = fmaxf(m, acc[ot][r]);
      if (g == 0) m = fmaxf(m, acc[6][r]);
      m = fmaxf(m, __shfl_xor(m, 16));
      m = fmaxf(m, __shfl_xor(m, 32));
      float s = 0.f;
      float e[7];
#pragma unroll
      for (int ot = 0; ot < 7; ++ot) {
        bool val = (ot < 6) || (g == 0);
        e[ot] = val ? __expf(acc[ot][r] - m) : 0.f;
        s += e[ot];
      }
      s += __shfl_xor(s, 16);
      s += __shfl_xor(s, 32);
      float inv = 1.f / s;
#pragma unroll
      for (int ot = 0; ot < 7; ++ot) acc[ot][r] = e[ot] * inv;
    }

#pragma unroll
    for (int sh = 0; sh < 2; ++sh) {
      unsigned int* wq = wpack + ((size_t)((n * 2 + sh) * HW) + pix) * 28;
#pragma unroll
      for (int ot = 0; ot < 7; ++ot) {
        if ((ot < 6) || (g == 0)) {
          __half2 h2 = __floats2half2_rn(acc[ot][2 * sh], acc[ot][2 * sh + 1]);
          wq[ot * 4 + g] = *reinterpret_cast<unsigned int*>(&h2);
        }
      }
    }
  }
}

// ---------------------------------------------------------------------------
// Kernel 3: reassembly v9.
// Block = 4x32 output tile (2x16 input core, 6x20 halo) x 64 channels.
// -> output row segments = 16 px * 8 B = 128 B contiguous (full write eff).
// LDS 64ch x 6x20 f32 = 30.7 KB (linear: dword = 4*slot) -> 5 blocks/CU
// with __launch_bounds__(256,5). Order: stage-loads -> LDS-write ->
// weight-loads -> barrier (peak regs ~70). Quad mapping + packed-f16
// weights in named uint4s + inline v_fma_mix (r7 pattern, scratch-free).
// ---------------------------------------------------------------------------
#define TAP4(W, V, fv)                                                         \
  asm("v_fma_mix_f32 %0, %1, %2, %0 op_sel:[0,0,0] op_sel_hi:[1,0,0]"          \
      : "+v"(a00) : "v"(W), "v"(fv));                                          \
  asm("v_fma_mix_f32 %0, %1, %2, %0 op_sel:[1,0,0] op_sel_hi:[1,0,0]"          \
      : "+v"(a01) : "v"(W), "v"(fv));                                          \
  asm("v_fma_mix_f32 %0, %1, %2, %0 op_sel:[0,0,0] op_sel_hi:[1,0,0]"          \
      : "+v"(a10) : "v"(V), "v"(fv));                                          \
  asm("v_fma_mix_f32 %0, %1, %2, %0 op_sel:[1,0,0] op_sel_hi:[1,0,0]"          \
      : "+v"(a11) : "v"(V), "v"(fv));

#define ROW5(WA, WB, WC, WD, WE, VA, VB, VC, VD, VE, RP)                       \
  { const float* rr = (RP);                                                    \
    float g0 = rr[0], g1 = rr[1], g2 = rr[2], g3 = rr[3], g4 = rr[4];          \
    TAP4(WA, VA, g0) TAP4(WB, VB, g1) TAP4(WC, VC, g2)                         \
    TAP4(WD, VD, g3) TAP4(WE, VE, g4) }

__device__ __forceinline__ float4 load_slot20(const float* __restrict__ xb,
                                              int h0, int w0, int f,
                                              bool interior) {
  int c = f / 30, rem = f - c * 30, r = rem / 5, h = rem - r * 5;
  int gh = h0 - 2 + r, gw = w0 - 2 + h * 4;
  if (interior) {
    const float* gp = xb + (size_t)c * HW + gh * WW + gw;
    float2 lo = *(const float2*)gp;       // gw even -> 8B aligned
    float2 hi = *(const float2*)(gp + 2);
    return make_float4(lo.x, lo.y, hi.x, hi.y);
  }
  float v0 = 0.f, v1 = 0.f, v2 = 0.f, v3 = 0.f;
  if ((unsigned)gh < 64u) {
    const float* rowp = xb + (size_t)c * HW + gh * WW;
    if ((unsigned)(gw + 0) < 64u) v0 = rowp[gw + 0];
    if ((unsigned)(gw + 1) < 64u) v1 = rowp[gw + 1];
    if ((unsigned)(gw + 2) < 64u) v2 = rowp[gw + 2];
    if ((unsigned)(gw + 3) < 64u) v3 = rowp[gw + 3];
  }
  return make_float4(v0, v1, v2, v3);
}

__global__ __launch_bounds__(256, 5) void reassembly_kernel(
    const float* __restrict__ x, const unsigned int* __restrict__ wpack,
    float* __restrict__ out) {
  __shared__ float xp[64 * 120];        // [c][r:6][col:20], dword = 4*slot
  int tid = threadIdx.x;
  int bid = blockIdx.x;                 // tile(128) | n(4) | cg(4)
  int tile = bid & 127;
  int n = (bid >> 7) & 3;
  int cg = bid >> 9;                    // 64-channel group
  int tyi = tile >> 2, txi = tile & 3;  // 32 x 4 tiles of 4x32 outputs
  int ty0 = tyi * 4, tx0 = txi * 32;
  int h0 = ty0 >> 1, w0 = tx0 >> 1;     // input core base (2 rows x 16 cols)

  const float* xb = x + (size_t)(n * CI + cg * 64) * HW;
  bool interior = (tyi >= 1) && (tyi <= 30) && (txi >= 1) && (txi <= 2);

  // ---- stage: 1920 f4-slots (64ch x 6r x 5), 7.5 per thread
  float4 s0 = load_slot20(xb, h0, w0, tid,        interior);
  float4 s1 = load_slot20(xb, h0, w0, tid + 256,  interior);
  float4 s2 = load_slot20(xb, h0, w0, tid + 512,  interior);
  float4 s3 = load_slot20(xb, h0, w0, tid + 768,  interior);
  float4 s4 = load_slot20(xb, h0, w0, tid + 1024, interior);
  float4 s5 = load_slot20(xb, h0, w0, tid + 1280, interior);
  float4 s6 = load_slot20(xb, h0, w0, tid + 1536, interior);
  bool half = tid < 128;
  float4 s7 = half ? load_slot20(xb, h0, w0, tid + 1792, interior)
                   : make_float4(0.f, 0.f, 0.f, 0.f);
  *(float4*)(xp + 4 * (tid))        = s0;
  *(float4*)(xp + 4 * (tid + 256))  = s1;
  *(float4*)(xp + 4 * (tid + 512))  = s2;
  *(float4*)(xp + 4 * (tid + 768))  = s3;
  *(float4*)(xp + 4 * (tid + 1024)) = s4;
  *(float4*)(xp + 4 * (tid + 1280)) = s5;
  *(float4*)(xp + 4 * (tid + 1536)) = s6;
  if (half) *(float4*)(xp + 4 * (tid + 1792)) = s7;

  // ---- thread mapping + weight loads (hide under barrier drain)
  int cslot = tid >> 5;                 // 0..7
  int ip = tid & 31;                    // py(1b) | px(4b)
  int py = ip >> 4, px = ip & 15;
  int oy0 = ty0 + py * 2, ox0 = tx0 + px * 2;
  int ysrc = h0 + py, xA = w0 + px;

  const unsigned int* wq0 =
      wpack + ((size_t)((n * 2 + 0) * HW) + ysrc * 64 + xA) * 28;
  const unsigned int* wq1 =
      wpack + ((size_t)((n * 2 + 1) * HW) + ysrc * 64 + xA) * 28;
  uint4 A0 = *(const uint4*)(wq0 + 0);
  uint4 A1 = *(const uint4*)(wq0 + 4);
  uint4 A2 = *(const uint4*)(wq0 + 8);
  uint4 A3 = *(const uint4*)(wq0 + 12);
  uint4 A4 = *(const uint4*)(wq0 + 16);
  uint4 A5 = *(const uint4*)(wq0 + 20);
  unsigned int A6 = wq0[24];
  uint4 B0 = *(const uint4*)(wq1 + 0);
  uint4 B1 = *(const uint4*)(wq1 + 4);
  uint4 B2 = *(const uint4*)(wq1 + 8);
  uint4 B3 = *(const uint4*)(wq1 + 12);
  uint4 B4 = *(const uint4*)(wq1 + 16);
  uint4 B5 = *(const uint4*)(wq1 + 20);
  unsigned int B6 = wq1[24];

  __syncthreads();

  // ---- compute: 8 channel-iters, quad of outputs per iter
  float* outb = out + ((size_t)(n * CI + cg * 64) * HS + oy0) * WS_ + ox0;
  for (int it = 0; it < 8; ++it) {
    int cl = it * 8 + cslot;
    const float* p = xp + cl * 120 + py * 20 + px;
    float a00 = 0.f, a01 = 0.f, a10 = 0.f, a11 = 0.f;
    ROW5(A0.x, A0.y, A0.z, A0.w, A1.x, B0.x, B0.y, B0.z, B0.w, B1.x, p)
    ROW5(A1.y, A1.z, A1.w, A2.x, A2.y, B1.y, B1.z, B1.w, B2.x, B2.y, p + 20)
    ROW5(A2.z, A2.w, A3.x, A3.y, A3.z, B2.z, B2.w, B3.x, B3.y, B3.z, p + 40)
    ROW5(A3.w, A4.x, A4.y, A4.z, A4.w, B3.w, B4.x, B4.y, B4.z, B4.w, p + 60)
    ROW5(A5.x, A5.y, A5.z, A5.w, A6,   B5.x, B5.y, B5.z, B5.w, B6,   p + 80)
    float* ob = outb + (size_t)cl * HS * WS_;
    *(float2*)(ob)       = make_float2(a00, a01);
    *(float2*)(ob + WS_) = make_float2(a10, a11);
  }
}

// ---------------------------------------------------------------------------
extern "C" void kernel_launch(void* const* d_in, const int* in_sizes, int n_in,
                              void* d_out, int out_size, void* d_ws,
                              size_t ws_size, hipStream_t stream) {
  const float* x      = (const float*)d_in[0];
  const float* w_comp = (const float*)d_in[1];
  const float* b_comp = (const float*)d_in[2];
  const float* w_enc  = (const float*)d_in[3];
  const float* b_enc  = (const float*)d_in[4];
  float* out = (float*)d_out;

  char* ws = (char*)d_ws;
  unsigned short* comp_cl = (unsigned short*)ws;                  // 2,097,152 B
  unsigned short* Aw1     = (unsigned short*)(ws + 2097152);      //    32,768 B
  unsigned short* Aw2     = (unsigned short*)(ws + 2129920);      //   129,024 B
  unsigned int*   wpack   = (unsigned int*)(ws + 2359296);        // 3,670,016 B

  prep_kernel<<<dim3(316), 256, 0, stream>>>(w_comp, w_enc, Aw1, Aw2);
  conv1x1_mfma<<<dim3(512), 512, 0, stream>>>(x, Aw1, b_comp, comp_cl);
  kenc_mfma<<<dim3(512), 512, 0, stream>>>(comp_cl, Aw2, b_enc, wpack);
  reassembly_kernel<<<dim3(2048), 256, 0, stream>>>(x, wpack, out);
}